// Round 5
// baseline (524.758 us; speedup 1.0000x reference)
//
#include <hip/hip_runtime.h>
#include <hip/hip_cooperative_groups.h>

namespace cg = cooperative_groups;

// AssociativeScanGateLoop: h_t = f_t*h_{t-1} + i_t*v_t per (b,d) sequence.
// x: (B=4, T=8192, 3*512) fp32.  out: (4, 8192, 512) fp32.
// ONE cooperative kernel, hierarchical chunked scan:
//   P1: per-chunk affine aggregates (A, KV) over Tc=32 steps (reads cols 0,1).
//   P2: 32 groups/batch of 8 chunks: serial scan within group -> per-chunk
//       exclusive local prefix (affine) + group aggregate.     [grid.sync]
//   P3: every block folds <=31 group aggregates (tiny, L2-hot), composes its
//       local prefix, recomputes its chunk and writes the gated output.
// 1024 blocks x 128 threads = 4 blocks/CU — safely co-resident for
// hipLaunchCooperativeKernel.

#define B_    4
#define T_    8192
#define ROW4_ 384   // 1536 floats per (b,t) row = 384 float4
#define DG4_  128   // 512 channels = 128 float4
#define C_    256   // chunks per batch
#define TC_   (T_ / C_)   // 32 steps per chunk
#define G_    32    // groups per batch
#define GS_   (C_ / G_)   // 8 chunks per group

__device__ __forceinline__ float sigmoid_f(float x) {
    return __fdividef(1.0f, 1.0f + __expf(-x));   // saturates gracefully
}
__device__ __forceinline__ float tanh_f(float x) {
    return 1.0f - __fdividef(2.0f, __expf(2.0f * x) + 1.0f);
}

__device__ __forceinline__ void step_agg(float xv, float gv, float& A, float& K) {
    const float s = sigmoid_f(gv);     // input gate
    const float f = 1.0f - s;          // forget gate
    A = f * A;
    K = f * K + tanh_f(xv) * s;
}

__device__ __forceinline__ void affine4(float4& h, const float4 a, const float4 kv) {
    h.x = a.x * h.x + kv.x;
    h.y = a.y * h.y + kv.y;
    h.z = a.z * h.z + kv.z;
    h.w = a.w * h.w + kv.w;
}

__global__ __launch_bounds__(128, 4) void scan_coop(
        const float4* __restrict__ x4,
        float4* __restrict__ out4,
        float4* __restrict__ aggA,   // [B_,C_,DG4_] chunk aggregates
        float4* __restrict__ aggKV,
        float4* __restrict__ locA,   // [B_,C_,DG4_] exclusive local prefix (affine)
        float4* __restrict__ locKV,
        float4* __restrict__ grpA,   // [B_,G_,DG4_] group aggregates
        float4* __restrict__ grpKV) {
    const int c  = blockIdx.x;           // chunk
    const int b  = blockIdx.y;           // batch
    const int d4 = threadIdx.x;          // 128 threads x 4 channels
    const float4* xb = x4 + (size_t)b * T_ * ROW4_;
    const int t0 = c * TC_;
    cg::grid_group grid = cg::this_grid();

    // ---- P1: chunk aggregate (reads cols 0,1) ----
    {
        float4 A  = make_float4(1.0f, 1.0f, 1.0f, 1.0f);
        float4 KV = make_float4(0.0f, 0.0f, 0.0f, 0.0f);
#pragma unroll 4
        for (int i = 0; i < TC_; ++i) {
            const size_t r = (size_t)(t0 + i) * ROW4_ + d4;
            const float4 xi = xb[r];
            const float4 gi = xb[r + DG4_];
            step_agg(xi.x, gi.x, A.x, KV.x);
            step_agg(xi.y, gi.y, A.y, KV.y);
            step_agg(xi.z, gi.z, A.z, KV.z);
            step_agg(xi.w, gi.w, A.w, KV.w);
        }
        const size_t idx = ((size_t)b * C_ + c) * DG4_ + d4;
        aggA[idx]  = A;
        aggKV[idx] = KV;
    }

    grid.sync();

    // ---- P2: within-group serial scan (blocks with c < G_ work; g = c) ----
    if (c < G_) {
        const int g = c;
        float4 A  = make_float4(1.0f, 1.0f, 1.0f, 1.0f);
        float4 KV = make_float4(0.0f, 0.0f, 0.0f, 0.0f);
#pragma unroll
        for (int j = 0; j < GS_; ++j) {
            const size_t idx = ((size_t)b * C_ + g * GS_ + j) * DG4_ + d4;
            locA[idx]  = A;              // exclusive prefix within group
            locKV[idx] = KV;
            const float4 ca = aggA[idx];
            const float4 ck = aggKV[idx];
            // compose: new = chunk_agg o current  (apply current first)
            A.x = ca.x * A.x;  KV.x = ca.x * KV.x + ck.x;
            A.y = ca.y * A.y;  KV.y = ca.y * KV.y + ck.y;
            A.z = ca.z * A.z;  KV.z = ca.z * KV.z + ck.z;
            A.w = ca.w * A.w;  KV.w = ca.w * KV.w + ck.w;
        }
        const size_t gidx = ((size_t)b * G_ + g) * DG4_ + d4;
        grpA[gidx]  = A;
        grpKV[gidx] = KV;
    }

    grid.sync();

    // ---- P3: fold group prefixes, compose local prefix, apply chunk ----
    const int g = c / GS_;
    float4 h = make_float4(0.0f, 0.0f, 0.0f, 0.0f);
    for (int gg = 0; gg < g; ++gg) {       // <=31 L2-hot iterations
        const size_t gidx = ((size_t)b * G_ + gg) * DG4_ + d4;
        affine4(h, grpA[gidx], grpKV[gidx]);
    }
    {
        const size_t idx = ((size_t)b * C_ + c) * DG4_ + d4;
        affine4(h, locA[idx], locKV[idx]);  // h entering this chunk
    }

    float4* ob = out4 + (size_t)b * T_ * DG4_;
#pragma unroll 4
    for (int i = 0; i < TC_; ++i) {
        const size_t r = (size_t)(t0 + i) * ROW4_ + d4;
        const float4 xi = xb[r];
        const float4 gi = xb[r + DG4_];
        const float4 go = xb[r + 2 * DG4_];
        float4 o;
        {
            const float s = sigmoid_f(gi.x), f = 1.0f - s;
            h.x = f * h.x + tanh_f(xi.x) * s;
            o.x = tanh_f(h.x) * sigmoid_f(go.x);
        }
        {
            const float s = sigmoid_f(gi.y), f = 1.0f - s;
            h.y = f * h.y + tanh_f(xi.y) * s;
            o.y = tanh_f(h.y) * sigmoid_f(go.y);
        }
        {
            const float s = sigmoid_f(gi.z), f = 1.0f - s;
            h.z = f * h.z + tanh_f(xi.z) * s;
            o.z = tanh_f(h.z) * sigmoid_f(go.z);
        }
        {
            const float s = sigmoid_f(gi.w), f = 1.0f - s;
            h.w = f * h.w + tanh_f(xi.w) * s;
            o.w = tanh_f(h.w) * sigmoid_f(go.w);
        }
        ob[(size_t)(t0 + i) * DG4_ + d4] = o;
    }
}

extern "C" void kernel_launch(void* const* d_in, const int* in_sizes, int n_in,
                              void* d_out, int out_size, void* d_ws, size_t ws_size,
                              hipStream_t stream) {
    const float4* x4 = (const float4*)d_in[0];
    float4* out4 = (float4*)d_out;

    const size_t NC = (size_t)B_ * C_ * DG4_;   // 131072 float4 = 2 MiB
    const size_t NG = (size_t)B_ * G_ * DG4_;   // 16384 float4
    float4* aggA  = (float4*)d_ws;
    float4* aggKV = aggA  + NC;
    float4* locA  = aggKV + NC;
    float4* locKV = locA  + NC;
    float4* grpA  = locKV + NC;
    float4* grpKV = grpA  + NG;

    void* args[] = { (void*)&x4, (void*)&out4,
                     (void*)&aggA, (void*)&aggKV,
                     (void*)&locA, (void*)&locKV,
                     (void*)&grpA, (void*)&grpKV };
    hipLaunchCooperativeKernel((const void*)scan_coop,
                               dim3(C_, B_), dim3(128), args, 0, stream);
}